// Round 11
// baseline (78.029 us; speedup 1.0000x reference)
//
#include <hip/hip_runtime.h>

typedef unsigned short u16;
typedef unsigned int u32;

#define B_   4
#define C_   256
#define CI_  128
#define H_   64
#define W_   64
#define NPB_ 4096     // pixels per batch image
#define NP_  16384    // total pixels
#define K_   9        // 3x3 taps
#define MROWS_ 272    // 128 q + 128 k + 1 wcomb + 15 pad

typedef __attribute__((ext_vector_type(8))) __bf16 bf16x8_t;
typedef __attribute__((ext_vector_type(4))) float f32x4_t;

__device__ __forceinline__ u16 f2bf(float f) {  // round-to-nearest-even
    union { float f; u32 i; } x; x.f = f;
    u32 lsb = (x.i >> 16) & 1u;
    return (u16)((x.i + 0x7fffu + lsb) >> 16);
}

// k0b: prepare Wt in FRAGMENT-TILED layout + bias[272].
// Wt[((mt*8+kk)*64 + g*16 + l16)*8 + e] = Wrow(mt*16+l16)[kk*32+g*8+e]
__global__ void k0b_prep(const float* __restrict__ Wq, const float* __restrict__ bq,
                         const float* __restrict__ Wk, const float* __restrict__ bk,
                         const float* __restrict__ Wv, const float* __restrict__ bv,
                         const float* __restrict__ Wo,
                         u16* __restrict__ Wt, float* __restrict__ bias) {
    const int o = blockIdx.x;   // 0..271 (row)
    const int c = threadIdx.x;  // 0..255 (channel)
    u16 val;
    if (o < 128) {
        val = f2bf(Wq[o * C_ + c]);
        if (c == 0) bias[o] = bq[o];
    } else if (o < 256) {
        val = f2bf(Wk[(o - 128) * C_ + c]);
        if (c == 0) bias[o] = bk[o - 128];
    } else if (o == 256) {
        float s = 0.f;
        #pragma unroll 8
        for (int oo = 0; oo < CI_; ++oo)
            s += Wo[oo] * Wv[oo * C_ + c];
        val = f2bf(s);
        if (c == 0) {
            float ts = 0.f;
            #pragma unroll 8
            for (int oo = 0; oo < CI_; ++oo) ts += Wo[oo] * bv[oo];
            bias[256] = ts;
        }
    } else {
        val = 0;
        if (c == 0) bias[o] = 0.f;
    }
    const int mt = o >> 4, l16 = o & 15;
    const int kk = c >> 5, g = (c >> 3) & 3, e = c & 7;
    Wt[(size_t)((mt * 8 + kk) * 64 + g * 16 + l16) * 8 + e] = val;
}

// k1: MFMA GEMM, branch-free. 8 waves/block, wave w owns m-tiles {2w,2w+1,16}
// (tile 16 = vs row, computed redundantly, written by wave 0 only). A-loads
// are 1KB coalesced wave loads from tiled Wt; B-frags via one ds_read_b128
// from a 16x272 bf16 LDS x-tile. D map: col(px)=l&15, row=(l>>4)*4+r (m89).
__global__ __launch_bounds__(512) void k1_proj(
    const float* __restrict__ x, const u16* __restrict__ Wt,
    const float* __restrict__ bias,
    u16* __restrict__ qk, float* __restrict__ vs) {
    __shared__ u16 xs[16][272];                          // row 544 B (16B-mult)
    const int t = threadIdx.x;
    const int l = t & 63;
    const int w = t >> 6;                                // wave 0..7
    const int lane16 = l & 15;
    const int g = l >> 4;
    const int p0 = blockIdx.x * 16;
    const int b = p0 >> 12;
    const int pin = p0 & 4095;

    {   // stage: thread t -> pixel t&15, channels (t>>4)*8 .. +7
        const int spx = t & 15, cg = t >> 4;             // cg 0..31
        const float* src = x + (size_t)(b * C_ + cg * 8) * NPB_ + pin + spx;
        float v[8];
        #pragma unroll
        for (int i = 0; i < 8; ++i) v[i] = src[(size_t)i * NPB_];
        uint4 pk;
        pk.x = (u32)f2bf(v[0]) | ((u32)f2bf(v[1]) << 16);
        pk.y = (u32)f2bf(v[2]) | ((u32)f2bf(v[3]) << 16);
        pk.z = (u32)f2bf(v[4]) | ((u32)f2bf(v[5]) << 16);
        pk.w = (u32)f2bf(v[6]) | ((u32)f2bf(v[7]) << 16);
        *reinterpret_cast<uint4*>(&xs[spx][cg * 8]) = pk;
    }
    __syncthreads();

    const int mts[3] = {2 * w, 2 * w + 1, 16};
    f32x4_t acc[3];
    #pragma unroll
    for (int n = 0; n < 3; ++n)
        #pragma unroll
        for (int r = 0; r < 4; ++r)
            acc[n][r] = bias[mts[n] * 16 + g * 4 + r];

    #pragma unroll
    for (int kk = 0; kk < 8; ++kk) {                     // K = 256, step 32
        const bf16x8_t bv = *reinterpret_cast<const bf16x8_t*>(&xs[lane16][kk * 32 + g * 8]);
        #pragma unroll
        for (int n = 0; n < 3; ++n) {
            const bf16x8_t av = *reinterpret_cast<const bf16x8_t*>(
                Wt + (size_t)((mts[n] * 8 + kk) * 64 + l) * 8);
            acc[n] = __builtin_amdgcn_mfma_f32_16x16x32_bf16(av, bv, acc[n], 0, 0, 0);
        }
    }

    // epilogue
    const int px = p0 + lane16;
    u16* qrow = qk + (size_t)px * C_;
    #pragma unroll
    for (int n = 0; n < 2; ++n) {
        const int mt = mts[n];
        u32* dst = reinterpret_cast<u32*>(qrow + mt * 16 + g * 4);
        dst[0] = (u32)f2bf(acc[n][0]) | ((u32)f2bf(acc[n][1]) << 16);
        dst[1] = (u32)f2bf(acc[n][2]) | ((u32)f2bf(acc[n][3]) << 16);
    }
    if (w == 0 && g == 0) vs[px] = acc[2][0];   // row 256 = vs
}

// k2 (G-matrix): one wave per pixel. By linearity,
//   S[i][j] = sum_{ca,cb} w[i,ca] w[j,cb] G[4j+ca...]  with
//   G[a][b] = k(corner a) . q(corner b)  over 128 channels (raw, unweighted).
// Corner rows in qkbuf are ALREADY bf16 -> loads feed MFMA directly (zero
// per-channel VALU). 48x48 padded G = 3x3 tiles x 4 k-steps = 36 MFMA.
// Lane l = (hi = l>>4, csub = (l&15)>>2, cnr = l&3): owns corner cnr of taps
// {csub, 4+csub, 8+csub} (clamped; w=0 if invalid == ref's valid-mask).
// Tile (ta,tb): A-row a = ta*16 + (l&15) = k-corner, B-col b = tb*16+(l&15)
// = q-corner (lane loads its own corner's k/q rows). D: col=l&15,
// row=hi*4+r (m89) -> lane holds G[a=ta*16+hi*4+r][b=tb*16+l&15].
// Contraction: col-weights = own w[tb], corner-sum via shfl_xor(1,2);
// row-weights via bpermute from lane 20*hi+r; softmax over j=ta*4+hi via
// shfl_xor(16,32) (verified pattern).
__global__ __launch_bounds__(256) void k2_attn(
    const float* __restrict__ off, const u16* __restrict__ qk,
    const float* __restrict__ vs, const float* __restrict__ bo,
    float* __restrict__ out) {
    const int t = threadIdx.x;
    const int l = t & 63;
    const int bid = blockIdx.x;
    const int swz = (bid & 7) * ((int)gridDim.x >> 3) + (bid >> 3);  // XCD-contiguous
    const int pixel = swz * 4 + (t >> 6);
    const int b = pixel >> 12;
    const int rem = pixel & 4095;
    const int y = rem >> 6, xx = rem & 63;
    const int lo = l & 15;
    const int hi = l >> 4;
    const int csub = lo >> 2;       // tap sub-index within a 4-tap tile group
    const int cnr = lo & 3;         // corner: dy = cnr>>1, dx = cnr&1

    const float* vsm = vs + (b << 12);
    const u16* qkb = qk + ((size_t)(b << 12)) * C_;

    // geometry for taps tt*4+csub (tt=0,1,2), this lane's corner only
    float w[3]; float vsuc[3]; const u16* rowp[3];
    #pragma unroll
    for (int tt = 0; tt < 3; ++tt) {
        int tap = tt * 4 + csub;
        const int tv = (tap < K_);
        if (!tv) tap = K_ - 1;                      // clamp (weight forced 0)
        const float* offb = off + ((size_t)b * (2 * K_) + 2 * tap) * NPB_ + rem;
        const float oy = offb[0];
        const float ox = offb[NPB_];
        const float py = (float)(y + tap / 3 - 1) + oy;
        const float px = (float)(xx + tap % 3 - 1) + ox;
        const float fy0 = floorf(py), fx0 = floorf(px);
        const float fy = py - fy0, fx = px - fx0;
        const int dy = cnr >> 1, dx = cnr & 1;
        const int yi = (int)fy0 + dy, xi = (int)fx0 + dx;
        const float wv = (dy ? fy : 1.f - fy) * (dx ? fx : 1.f - fx);
        const int ok = (yi >= 0) & (yi < H_) & (xi >= 0) & (xi < W_) & tv;
        const int yc = min(max(yi, 0), H_ - 1);
        const int xc = min(max(xi, 0), W_ - 1);
        const int pp = yc * W_ + xc;
        w[tt] = ok ? wv : 0.f;
        vsuc[tt] = w[tt] * vsm[pp];
        rowp[tt] = qkb + (size_t)pp * C_ + hi * 8;
    }
    // vsu per tap group (sum over 4 corner lanes), replicated
    #pragma unroll
    for (int tt = 0; tt < 3; ++tt) {
        vsuc[tt] += __shfl_xor(vsuc[tt], 1, 64);
        vsuc[tt] += __shfl_xor(vsuc[tt], 2, 64);
    }
    // row weights: w(tap ta*4+hi, corner r) from lane 20*hi + r
    float wrow[3][4];
    #pragma unroll
    for (int ta = 0; ta < 3; ++ta)
        #pragma unroll
        for (int r = 0; r < 4; ++r)
            wrow[ta][r] = __shfl(w[ta], 20 * hi + r, 64);
    // vsu[j = ta*4+hi] from lane 20*hi
    float vsj[3];
    #pragma unroll
    for (int ta = 0; ta < 3; ++ta)
        vsj[ta] = __shfl(vsuc[ta], 20 * hi, 64);

    // G accumulation: 3x3 tiles, K = 128 channels = 4 MFMA steps
    f32x4_t acc[3][3];
    #pragma unroll
    for (int ta = 0; ta < 3; ++ta)
        #pragma unroll
        for (int tb = 0; tb < 3; ++tb)
            acc[ta][tb] = (f32x4_t){0.f, 0.f, 0.f, 0.f};
    #pragma unroll
    for (int s = 0; s < 4; ++s) {
        bf16x8_t qf[3], kf[3];
        #pragma unroll
        for (int tt = 0; tt < 3; ++tt) {
            qf[tt] = *reinterpret_cast<const bf16x8_t*>(rowp[tt] + s * 32);         // q row
            kf[tt] = *reinterpret_cast<const bf16x8_t*>(rowp[tt] + CI_ + s * 32);   // k row
        }
        #pragma unroll
        for (int ta = 0; ta < 3; ++ta)
            #pragma unroll
            for (int tb = 0; tb < 3; ++tb)
                acc[ta][tb] = __builtin_amdgcn_mfma_f32_16x16x32_bf16(
                    kf[ta], qf[tb], acc[ta][tb], 0, 0, 0);
    }

    // contraction: S[i = tb*4+csub][j = ta*4+hi]
    float Sv[3][3];   // [tb][ta]
    #pragma unroll
    for (int ta = 0; ta < 3; ++ta) {
        #pragma unroll
        for (int tb = 0; tb < 3; ++tb) {
            float s0 = 0.f;
            #pragma unroll
            for (int r = 0; r < 4; ++r) {
                float u = acc[ta][tb][r] * w[tb];   // q-side (col) weight
                u += __shfl_xor(u, 1, 64);          // sum q-corner group
                u += __shfl_xor(u, 2, 64);
                s0 += wrow[ta][r] * u;              // k-side (row) weight
            }
            Sv[tb][ta] = s0;
        }
    }

    // softmax over j (= ta regs x hi lane groups); independent per i (tb reg)
    const float bof = bo[0];
    float outv[3];
    #pragma unroll
    for (int tb = 0; tb < 3; ++tb) {
        float mx = -1e30f;
        #pragma unroll
        for (int ta = 0; ta < 3; ++ta)
            if (ta < 2) mx = fmaxf(mx, Sv[tb][ta]);
            else if (hi == 0) mx = fmaxf(mx, Sv[tb][ta]);
        mx = fmaxf(mx, __shfl_xor(mx, 16, 64));
        mx = fmaxf(mx, __shfl_xor(mx, 32, 64));
        float den = 0.f, num = 0.f;
        #pragma unroll
        for (int ta = 0; ta < 3; ++ta) {
            if (ta < 2 || hi == 0) {
                const float e = __expf(Sv[tb][ta] - mx);
                den += e;
                num += e * vsj[ta];
            }
        }
        den += __shfl_xor(den, 16, 64); den += __shfl_xor(den, 32, 64);
        num += __shfl_xor(num, 16, 64); num += __shfl_xor(num, 32, 64);
        outv[tb] = num / den + bof;
    }

    // write: lanes cnr==0 && hi==0 (l = 0,4,8,12); i = tb*4 + csub
    if (cnr == 0 && hi == 0) {
        #pragma unroll
        for (int tb = 0; tb < 3; ++tb) {
            const int i = tb * 4 + csub;
            if (i < K_)
                out[(size_t)b * K_ * NPB_ + (size_t)i * NPB_ + rem] =
                    1.f / (1.f + __expf(-outv[tb]));
        }
    }
}

extern "C" void kernel_launch(void* const* d_in, const int* in_sizes, int n_in,
                              void* d_out, int out_size, void* d_ws, size_t ws_size,
                              hipStream_t stream) {
    const float* x   = (const float*)d_in[0];
    const float* off = (const float*)d_in[1];
    const float* Wq  = (const float*)d_in[2];
    const float* bq  = (const float*)d_in[3];
    const float* Wk  = (const float*)d_in[4];
    const float* bk  = (const float*)d_in[5];
    const float* Wv  = (const float*)d_in[6];
    const float* bv  = (const float*)d_in[7];
    const float* Wo  = (const float*)d_in[8];
    const float* bo  = (const float*)d_in[9];
    float* out = (float*)d_out;

    char* ws = (char*)d_ws;
    u16*   qkbuf = (u16*)(ws + 4096);                 // 16384*256 bf16 = 8 MiB
    float* vsmap = (float*)(ws + 4096 + 8388608);     // 16384 f32 = 64 KiB
    u16*   Wt    = (u16*)(ws + 4096 + 8388608 + 65536);        // 272*256 bf16 tiled
    float* bias  = (float*)(ws + 4096 + 8388608 + 65536 + 139264);  // 272 f32

    k0b_prep<<<MROWS_, 256, 0, stream>>>(Wq, bq, Wk, bk, Wv, bv, Wo, Wt, bias);
    k1_proj<<<NP_ / 16, 512, 0, stream>>>(x, Wt, bias, qkbuf, vsmap);
    k2_attn<<<NP_ / 4, 256, 0, stream>>>(off, qkbuf, vsmap, bo, out);
}

// Round 12
// 77.827 us; speedup vs baseline: 1.0026x; 1.0026x over previous
//
#include <hip/hip_runtime.h>

typedef unsigned short u16;
typedef unsigned int u32;

#define B_   4
#define C_   256
#define CI_  128
#define H_   64
#define W_   64
#define NPB_ 4096     // pixels per batch image
#define NP_  16384    // total pixels
#define K_   9        // 3x3 taps
#define MROWS_ 272    // 128 q + 128 k + 1 wcomb + 15 pad

typedef __attribute__((ext_vector_type(8))) __bf16 bf16x8_t;
typedef __attribute__((ext_vector_type(4))) float f32x4_t;

__device__ __forceinline__ u16 f2bf(float f) {  // round-to-nearest-even
    union { float f; u32 i; } x; x.f = f;
    u32 lsb = (x.i >> 16) & 1u;
    return (u16)((x.i + 0x7fffu + lsb) >> 16);
}

// k0b: prepare Wt in FRAGMENT-TILED layout + bias[272].
// Wt[((mt*8+kk)*64 + g*16 + l16)*8 + e] = Wrow(mt*16+l16)[kk*32+g*8+e]
__global__ void k0b_prep(const float* __restrict__ Wq, const float* __restrict__ bq,
                         const float* __restrict__ Wk, const float* __restrict__ bk,
                         const float* __restrict__ Wv, const float* __restrict__ bv,
                         const float* __restrict__ Wo,
                         u16* __restrict__ Wt, float* __restrict__ bias) {
    const int o = blockIdx.x;   // 0..271 (row)
    const int c = threadIdx.x;  // 0..255 (channel)
    u16 val;
    if (o < 128) {
        val = f2bf(Wq[o * C_ + c]);
        if (c == 0) bias[o] = bq[o];
    } else if (o < 256) {
        val = f2bf(Wk[(o - 128) * C_ + c]);
        if (c == 0) bias[o] = bk[o - 128];
    } else if (o == 256) {
        float s = 0.f;
        #pragma unroll 8
        for (int oo = 0; oo < CI_; ++oo)
            s += Wo[oo] * Wv[oo * C_ + c];
        val = f2bf(s);
        if (c == 0) {
            float ts = 0.f;
            #pragma unroll 8
            for (int oo = 0; oo < CI_; ++oo) ts += Wo[oo] * bv[oo];
            bias[256] = ts;
        }
    } else {
        val = 0;
        if (c == 0) bias[o] = 0.f;
    }
    const int mt = o >> 4, l16 = o & 15;
    const int kk = c >> 5, g = (c >> 3) & 3, e = c & 7;
    Wt[(size_t)((mt * 8 + kk) * 64 + g * 16 + l16) * 8 + e] = val;
}

// k1: MFMA GEMM, branch-free. 8 waves/block, wave w owns m-tiles {2w,2w+1,16}
// (tile 16 = vs row, computed redundantly, written by wave 0 only). A-loads
// are 1KB coalesced wave loads from tiled Wt; B-frags via one ds_read_b128
// from a 16x272 bf16 LDS x-tile. D map: col(px)=l&15, row=(l>>4)*4+r (m89).
__global__ __launch_bounds__(512) void k1_proj(
    const float* __restrict__ x, const u16* __restrict__ Wt,
    const float* __restrict__ bias,
    u16* __restrict__ qk, float* __restrict__ vs) {
    __shared__ u16 xs[16][272];                          // row 544 B (16B-mult)
    const int t = threadIdx.x;
    const int l = t & 63;
    const int w = t >> 6;                                // wave 0..7
    const int lane16 = l & 15;
    const int g = l >> 4;
    const int p0 = blockIdx.x * 16;
    const int b = p0 >> 12;
    const int pin = p0 & 4095;

    {   // stage: thread t -> pixel t&15, channels (t>>4)*8 .. +7
        const int spx = t & 15, cg = t >> 4;             // cg 0..31
        const float* src = x + (size_t)(b * C_ + cg * 8) * NPB_ + pin + spx;
        float v[8];
        #pragma unroll
        for (int i = 0; i < 8; ++i) v[i] = src[(size_t)i * NPB_];
        uint4 pk;
        pk.x = (u32)f2bf(v[0]) | ((u32)f2bf(v[1]) << 16);
        pk.y = (u32)f2bf(v[2]) | ((u32)f2bf(v[3]) << 16);
        pk.z = (u32)f2bf(v[4]) | ((u32)f2bf(v[5]) << 16);
        pk.w = (u32)f2bf(v[6]) | ((u32)f2bf(v[7]) << 16);
        *reinterpret_cast<uint4*>(&xs[spx][cg * 8]) = pk;
    }
    __syncthreads();

    const int mts[3] = {2 * w, 2 * w + 1, 16};
    f32x4_t acc[3];
    #pragma unroll
    for (int n = 0; n < 3; ++n)
        #pragma unroll
        for (int r = 0; r < 4; ++r)
            acc[n][r] = bias[mts[n] * 16 + g * 4 + r];

    #pragma unroll
    for (int kk = 0; kk < 8; ++kk) {                     // K = 256, step 32
        const bf16x8_t bv = *reinterpret_cast<const bf16x8_t*>(&xs[lane16][kk * 32 + g * 8]);
        #pragma unroll
        for (int n = 0; n < 3; ++n) {
            const bf16x8_t av = *reinterpret_cast<const bf16x8_t*>(
                Wt + (size_t)((mts[n] * 8 + kk) * 64 + l) * 8);
            acc[n] = __builtin_amdgcn_mfma_f32_16x16x32_bf16(av, bv, acc[n], 0, 0, 0);
        }
    }

    // epilogue
    const int px = p0 + lane16;
    u16* qrow = qk + (size_t)px * C_;
    #pragma unroll
    for (int n = 0; n < 2; ++n) {
        const int mt = mts[n];
        u32* dst = reinterpret_cast<u32*>(qrow + mt * 16 + g * 4);
        dst[0] = (u32)f2bf(acc[n][0]) | ((u32)f2bf(acc[n][1]) << 16);
        dst[1] = (u32)f2bf(acc[n][2]) | ((u32)f2bf(acc[n][3]) << 16);
    }
    if (w == 0 && g == 0) vs[px] = acc[2][0];   // row 256 = vs
}

// k2 (G-matrix): one wave per pixel. By linearity,
//   S[i][j] = sum_{ca,cb} w[i,ca] w[j,cb] G[4j+ca...]  with
//   G[a][b] = k(corner a) . q(corner b)  over 128 channels (raw, unweighted).
// Corner rows in qkbuf are ALREADY bf16 -> loads feed MFMA directly (zero
// per-channel VALU). 48x48 padded G = 3x3 tiles x 4 k-steps = 36 MFMA.
// Lane l = (hi = l>>4, csub = (l&15)>>2, cnr = l&3): owns corner cnr of taps
// {csub, 4+csub, 8+csub} (clamped; w=0 if invalid == ref's valid-mask).
// Tile (ta,tb): A-row a = ta*16 + (l&15) = k-corner, B-col b = tb*16+(l&15)
// = q-corner (lane loads its own corner's k/q rows). D: col=l&15,
// row=hi*4+r (m89) -> lane holds G[a=ta*16+hi*4+r][b=tb*16+l&15].
// Contraction: col-weights = own w[tb], corner-sum via shfl_xor(1,2);
// row-weights via bpermute from lane 20*hi+r; softmax over j=ta*4+hi via
// shfl_xor(16,32) (verified pattern).
__global__ __launch_bounds__(256) void k2_attn(
    const float* __restrict__ off, const u16* __restrict__ qk,
    const float* __restrict__ vs, const float* __restrict__ bo,
    float* __restrict__ out) {
    const int t = threadIdx.x;
    const int l = t & 63;
    const int bid = blockIdx.x;
    const int swz = (bid & 7) * ((int)gridDim.x >> 3) + (bid >> 3);  // XCD-contiguous
    const int pixel = swz * 4 + (t >> 6);
    const int b = pixel >> 12;
    const int rem = pixel & 4095;
    const int y = rem >> 6, xx = rem & 63;
    const int lo = l & 15;
    const int hi = l >> 4;
    const int csub = lo >> 2;       // tap sub-index within a 4-tap tile group
    const int cnr = lo & 3;         // corner: dy = cnr>>1, dx = cnr&1

    const float* vsm = vs + (b << 12);
    const u16* qkb = qk + ((size_t)(b << 12)) * C_;

    // geometry for taps tt*4+csub (tt=0,1,2), this lane's corner only
    float w[3]; float vsuc[3]; const u16* rowp[3];
    #pragma unroll
    for (int tt = 0; tt < 3; ++tt) {
        int tap = tt * 4 + csub;
        const int tv = (tap < K_);
        if (!tv) tap = K_ - 1;                      // clamp (weight forced 0)
        const float* offb = off + ((size_t)b * (2 * K_) + 2 * tap) * NPB_ + rem;
        const float oy = offb[0];
        const float ox = offb[NPB_];
        const float py = (float)(y + tap / 3 - 1) + oy;
        const float px = (float)(xx + tap % 3 - 1) + ox;
        const float fy0 = floorf(py), fx0 = floorf(px);
        const float fy = py - fy0, fx = px - fx0;
        const int dy = cnr >> 1, dx = cnr & 1;
        const int yi = (int)fy0 + dy, xi = (int)fx0 + dx;
        const float wv = (dy ? fy : 1.f - fy) * (dx ? fx : 1.f - fx);
        const int ok = (yi >= 0) & (yi < H_) & (xi >= 0) & (xi < W_) & tv;
        const int yc = min(max(yi, 0), H_ - 1);
        const int xc = min(max(xi, 0), W_ - 1);
        const int pp = yc * W_ + xc;
        w[tt] = ok ? wv : 0.f;
        vsuc[tt] = w[tt] * vsm[pp];
        rowp[tt] = qkb + (size_t)pp * C_ + hi * 8;
    }
    // vsu per tap group (sum over 4 corner lanes), replicated
    #pragma unroll
    for (int tt = 0; tt < 3; ++tt) {
        vsuc[tt] += __shfl_xor(vsuc[tt], 1, 64);
        vsuc[tt] += __shfl_xor(vsuc[tt], 2, 64);
    }
    // row weights: w(tap ta*4+hi, corner r) from lane 20*hi + r
    float wrow[3][4];
    #pragma unroll
    for (int ta = 0; ta < 3; ++ta)
        #pragma unroll
        for (int r = 0; r < 4; ++r)
            wrow[ta][r] = __shfl(w[ta], 20 * hi + r, 64);
    // vsu[j = ta*4+hi] from lane 20*hi
    float vsj[3];
    #pragma unroll
    for (int ta = 0; ta < 3; ++ta)
        vsj[ta] = __shfl(vsuc[ta], 20 * hi, 64);

    // G accumulation: 3x3 tiles, K = 128 channels = 4 MFMA steps
    f32x4_t acc[3][3];
    #pragma unroll
    for (int ta = 0; ta < 3; ++ta)
        #pragma unroll
        for (int tb = 0; tb < 3; ++tb)
            acc[ta][tb] = (f32x4_t){0.f, 0.f, 0.f, 0.f};
    #pragma unroll
    for (int s = 0; s < 4; ++s) {
        bf16x8_t qf[3], kf[3];
        #pragma unroll
        for (int tt = 0; tt < 3; ++tt) {
            qf[tt] = *reinterpret_cast<const bf16x8_t*>(rowp[tt] + s * 32);         // q row
            kf[tt] = *reinterpret_cast<const bf16x8_t*>(rowp[tt] + CI_ + s * 32);   // k row
        }
        #pragma unroll
        for (int ta = 0; ta < 3; ++ta)
            #pragma unroll
            for (int tb = 0; tb < 3; ++tb)
                acc[ta][tb] = __builtin_amdgcn_mfma_f32_16x16x32_bf16(
                    kf[ta], qf[tb], acc[ta][tb], 0, 0, 0);
    }

    // contraction: S[i = tb*4+csub][j = ta*4+hi]
    float Sv[3][3];   // [tb][ta]
    #pragma unroll
    for (int ta = 0; ta < 3; ++ta) {
        #pragma unroll
        for (int tb = 0; tb < 3; ++tb) {
            float s0 = 0.f;
            #pragma unroll
            for (int r = 0; r < 4; ++r) {
                float u = acc[ta][tb][r] * w[tb];   // q-side (col) weight
                u += __shfl_xor(u, 1, 64);          // sum q-corner group
                u += __shfl_xor(u, 2, 64);
                s0 += wrow[ta][r] * u;              // k-side (row) weight
            }
            Sv[tb][ta] = s0;
        }
    }

    // softmax over j (= ta regs x hi lane groups); independent per i (tb reg)
    const float bof = bo[0];
    float outv[3];
    #pragma unroll
    for (int tb = 0; tb < 3; ++tb) {
        float mx = -1e30f;
        #pragma unroll
        for (int ta = 0; ta < 3; ++ta)
            if (ta < 2) mx = fmaxf(mx, Sv[tb][ta]);
            else if (hi == 0) mx = fmaxf(mx, Sv[tb][ta]);
        mx = fmaxf(mx, __shfl_xor(mx, 16, 64));
        mx = fmaxf(mx, __shfl_xor(mx, 32, 64));
        float den = 0.f, num = 0.f;
        #pragma unroll
        for (int ta = 0; ta < 3; ++ta) {
            if (ta < 2 || hi == 0) {
                const float e = __expf(Sv[tb][ta] - mx);
                den += e;
                num += e * vsj[ta];
            }
        }
        den += __shfl_xor(den, 16, 64); den += __shfl_xor(den, 32, 64);
        num += __shfl_xor(num, 16, 64); num += __shfl_xor(num, 32, 64);
        outv[tb] = num / den + bof;
    }

    // write: lanes cnr==0 && hi==0 (l = 0,4,8,12); i = tb*4 + csub
    if (cnr == 0 && hi == 0) {
        #pragma unroll
        for (int tb = 0; tb < 3; ++tb) {
            const int i = tb * 4 + csub;
            if (i < K_)
                out[(size_t)b * K_ * NPB_ + (size_t)i * NPB_ + rem] =
                    1.f / (1.f + __expf(-outv[tb]));
        }
    }
}

extern "C" void kernel_launch(void* const* d_in, const int* in_sizes, int n_in,
                              void* d_out, int out_size, void* d_ws, size_t ws_size,
                              hipStream_t stream) {
    const float* x   = (const float*)d_in[0];
    const float* off = (const float*)d_in[1];
    const float* Wq  = (const float*)d_in[2];
    const float* bq  = (const float*)d_in[3];
    const float* Wk  = (const float*)d_in[4];
    const float* bk  = (const float*)d_in[5];
    const float* Wv  = (const float*)d_in[6];
    const float* bv  = (const float*)d_in[7];
    const float* Wo  = (const float*)d_in[8];
    const float* bo  = (const float*)d_in[9];
    float* out = (float*)d_out;

    char* ws = (char*)d_ws;
    u16*   qkbuf = (u16*)(ws + 4096);                 // 16384*256 bf16 = 8 MiB
    float* vsmap = (float*)(ws + 4096 + 8388608);     // 16384 f32 = 64 KiB
    u16*   Wt    = (u16*)(ws + 4096 + 8388608 + 65536);        // 272*256 bf16 tiled
    float* bias  = (float*)(ws + 4096 + 8388608 + 65536 + 139264);  // 272 f32

    k0b_prep<<<MROWS_, 256, 0, stream>>>(Wq, bq, Wk, bk, Wv, bv, Wo, Wt, bias);
    k1_proj<<<NP_ / 16, 512, 0, stream>>>(x, Wt, bias, qkbuf, vsmap);
    k2_attn<<<NP_ / 4, 256, 0, stream>>>(off, qkbuf, vsmap, bo, out);
}

// Round 13
// 75.438 us; speedup vs baseline: 1.0343x; 1.0317x over previous
//
#include <hip/hip_runtime.h>

typedef unsigned short u16;
typedef unsigned int u32;

#define B_   4
#define C_   256
#define CI_  128
#define H_   64
#define W_   64
#define NPB_ 4096     // pixels per batch image
#define NP_  16384    // total pixels
#define K_   9        // 3x3 taps
#define MROWS_ 272    // 128 q + 128 k + 1 wcomb + 15 pad

typedef __attribute__((ext_vector_type(8))) __bf16 bf16x8_t;
typedef __attribute__((ext_vector_type(4))) float f32x4_t;
typedef __attribute__((ext_vector_type(2))) float f32x2_t;
typedef __attribute__((ext_vector_type(4))) u32 u32x4;

// forced-issue global load: volatile asm order is preserved, output regs are
// materialized by construction (compiler cannot re-sink the load to its use).
#define GLD(dst, p, immstr) \
    asm volatile("global_load_dwordx4 %0, %1, off offset:" immstr \
                 : "=v"(dst) : "v"(p))

__device__ __forceinline__ float bf2f_lo(u32 w) {
    union { u32 i; float f; } x; x.i = w << 16; return x.f;
}
__device__ __forceinline__ float bf2f_hi(u32 w) {
    union { u32 i; float f; } x; x.i = w & 0xffff0000u; return x.f;
}
__device__ __forceinline__ u16 f2bf(float f) {  // round-to-nearest-even
    union { float f; u32 i; } x; x.f = f;
    u32 lsb = (x.i >> 16) & 1u;
    return (u16)((x.i + 0x7fffu + lsb) >> 16);
}
// packed bilinear accumulate: 8 bf16 channels, f32x2 lanes -> v_pk_fma_f32
__device__ __forceinline__ void acc8p(f32x2_t* f, u32x4 v, f32x2_t w2) {
    f32x2_t p;
    p.x = bf2f_lo(v[0]); p.y = bf2f_hi(v[0]); f[0] += w2 * p;
    p.x = bf2f_lo(v[1]); p.y = bf2f_hi(v[1]); f[1] += w2 * p;
    p.x = bf2f_lo(v[2]); p.y = bf2f_hi(v[2]); f[2] += w2 * p;
    p.x = bf2f_lo(v[3]); p.y = bf2f_hi(v[3]); f[3] += w2 * p;
}

// k0b: prepare Wt in FRAGMENT-TILED layout + bias[272].
// Wt[((mt*8+kk)*64 + g*16 + l16)*8 + e] = Wrow(mt*16+l16)[kk*32+g*8+e]
__global__ void k0b_prep(const float* __restrict__ Wq, const float* __restrict__ bq,
                         const float* __restrict__ Wk, const float* __restrict__ bk,
                         const float* __restrict__ Wv, const float* __restrict__ bv,
                         const float* __restrict__ Wo,
                         u16* __restrict__ Wt, float* __restrict__ bias) {
    const int o = blockIdx.x;   // 0..271 (row)
    const int c = threadIdx.x;  // 0..255 (channel)
    u16 val;
    if (o < 128) {
        val = f2bf(Wq[o * C_ + c]);
        if (c == 0) bias[o] = bq[o];
    } else if (o < 256) {
        val = f2bf(Wk[(o - 128) * C_ + c]);
        if (c == 0) bias[o] = bk[o - 128];
    } else if (o == 256) {
        float s = 0.f;
        #pragma unroll 8
        for (int oo = 0; oo < CI_; ++oo)
            s += Wo[oo] * Wv[oo * C_ + c];
        val = f2bf(s);
        if (c == 0) {
            float ts = 0.f;
            #pragma unroll 8
            for (int oo = 0; oo < CI_; ++oo) ts += Wo[oo] * bv[oo];
            bias[256] = ts;
        }
    } else {
        val = 0;
        if (c == 0) bias[o] = 0.f;
    }
    const int mt = o >> 4, l16 = o & 15;
    const int kk = c >> 5, g = (c >> 3) & 3, e = c & 7;
    Wt[(size_t)((mt * 8 + kk) * 64 + g * 16 + l16) * 8 + e] = val;
}

// k1: MFMA GEMM. THIS ROUND: all 24 A-fragment loads forced-issued via asm
// BEFORE the x-stage (one vmcnt drain for everything), consumed from regs.
// Wave w owns m-tiles {2w,2w+1,16}. D map: col(px)=l&15, row=(l>>4)*4+r (m89).
__global__ __launch_bounds__(512) void k1_proj(
    const float* __restrict__ x, const u16* __restrict__ Wt,
    const float* __restrict__ bias,
    u16* __restrict__ qk, float* __restrict__ vs) {
    __shared__ u16 xs[16][272];                          // row 544 B (16B-mult)
    const int t = threadIdx.x;
    const int l = t & 63;
    const int w = t >> 6;                                // wave 0..7
    const int lane16 = l & 15;
    const int g = l >> 4;
    const int p0 = blockIdx.x * 16;
    const int b = p0 >> 12;
    const int pin = p0 & 4095;

    const int mts[3] = {2 * w, 2 * w + 1, 16};

    // ---- forced-issue ALL 24 A-fragment loads (payload 96 VGPR) ----
    u32x4 afr[8][3];
    #pragma unroll
    for (int n = 0; n < 3; ++n) {
        const u16* pA = Wt + ((size_t)(mts[n] * 8) * 64 + l) * 8;   // kk 0..3
        const u16* pB = pA + 4 * 64 * 8;                            // kk 4..7
        GLD(afr[0][n], pA, "0");    GLD(afr[1][n], pA, "1024");
        GLD(afr[2][n], pA, "2048"); GLD(afr[3][n], pA, "3072");
        GLD(afr[4][n], pB, "0");    GLD(afr[5][n], pB, "1024");
        GLD(afr[6][n], pB, "2048"); GLD(afr[7][n], pB, "3072");
    }

    {   // stage x: thread t -> pixel t&15, channels (t>>4)*8 .. +7
        const int spx = t & 15, cg = t >> 4;             // cg 0..31
        const float* src = x + (size_t)(b * C_ + cg * 8) * NPB_ + pin + spx;
        float v[8];
        #pragma unroll
        for (int i = 0; i < 8; ++i) v[i] = src[(size_t)i * NPB_];
        uint4 pk;
        pk.x = (u32)f2bf(v[0]) | ((u32)f2bf(v[1]) << 16);
        pk.y = (u32)f2bf(v[2]) | ((u32)f2bf(v[3]) << 16);
        pk.z = (u32)f2bf(v[4]) | ((u32)f2bf(v[5]) << 16);
        pk.w = (u32)f2bf(v[6]) | ((u32)f2bf(v[7]) << 16);
        *reinterpret_cast<uint4*>(&xs[spx][cg * 8]) = pk;
    }
    __syncthreads();
    asm volatile("s_waitcnt vmcnt(0)" ::: "memory");
    __builtin_amdgcn_sched_barrier(0);

    f32x4_t acc[3];
    #pragma unroll
    for (int n = 0; n < 3; ++n)
        #pragma unroll
        for (int r = 0; r < 4; ++r)
            acc[n][r] = bias[mts[n] * 16 + g * 4 + r];

    #pragma unroll
    for (int kk = 0; kk < 8; ++kk) {                     // K = 256, step 32
        const bf16x8_t bv = *reinterpret_cast<const bf16x8_t*>(&xs[lane16][kk * 32 + g * 8]);
        #pragma unroll
        for (int n = 0; n < 3; ++n) {
            const bf16x8_t av = __builtin_bit_cast(bf16x8_t, afr[kk][n]);
            acc[n] = __builtin_amdgcn_mfma_f32_16x16x32_bf16(av, bv, acc[n], 0, 0, 0);
        }
    }

    // epilogue
    const int px = p0 + lane16;
    u16* qrow = qk + (size_t)px * C_;
    #pragma unroll
    for (int n = 0; n < 2; ++n) {
        const int mt = mts[n];
        u32* dst = reinterpret_cast<u32*>(qrow + mt * 16 + g * 4);
        dst[0] = (u32)f2bf(acc[n][0]) | ((u32)f2bf(acc[n][1]) << 16);
        dst[1] = (u32)f2bf(acc[n][2]) | ((u32)f2bf(acc[n][3]) << 16);
    }
    if (w == 0 && g == 0) vs[px] = acc[2][0];   // row 256 = vs
}

// k2: round-9 structure (best so far) with the gather replaced by 32
// forced-issue asm loads + ONE vmcnt(0) drain + sched_barrier(0) (rule #18).
// lane l: tap = min(l&15,8), g = l>>4; branchless clamped gather, validity in
// weight (== ref valid-mask). A/B share (lane,elem)->k map so HW k-permutation
// cancels; C/D: col=l&15, row=(l>>4)*4+reg (m89). XCD-contiguous swizzle.
__global__ __launch_bounds__(256) void k2_attn(
    const float* __restrict__ off, const u16* __restrict__ qk,
    const float* __restrict__ vs, const float* __restrict__ bo,
    float* __restrict__ out) {
    const int t = threadIdx.x;
    const int l = t & 63;
    const int bid = blockIdx.x;
    const int swz = (bid & 7) * ((int)gridDim.x >> 3) + (bid >> 3);  // XCD-contiguous
    const int pixel = swz * 4 + (t >> 6);
    const int b = pixel >> 12;
    const int rem = pixel & 4095;
    const int y = rem >> 6, xx = rem & 63;
    const int l16 = l & 15;
    const int tap = (l16 < K_) ? l16 : (K_ - 1);
    const int g = l >> 4;

    const float* offb = off + ((size_t)b * (2 * K_) + 2 * tap) * NPB_ + rem;
    const float oy = offb[0];
    const float ox = offb[NPB_];
    const float py = (float)(y + tap / 3 - 1) + oy;
    const float px = (float)(xx + tap % 3 - 1) + ox;
    const float fy0 = floorf(py), fx0 = floorf(px);
    const float fy = py - fy0, fx = px - fx0;
    const int y0 = (int)fy0, x0 = (int)fx0;

    const u16* qkb = qk + ((size_t)(b << 12)) * C_ + g * 8;
    const float* vsm = vs + (b << 12);

    // 4 corner weights (validity-masked) + clamped base pointers
    float wgt[4];
    int ppc[4];
    const u16* bp[4];
    #pragma unroll
    for (int c = 0; c < 4; ++c) {
        const int dy = c >> 1, dx = c & 1;
        const int yi = y0 + dy, xi = x0 + dx;
        const float wv = (dy ? fy : 1.f - fy) * (dx ? fx : 1.f - fx);
        const int ok = (yi >= 0) & (yi < H_) & (xi >= 0) & (xi < W_);
        const int yc = min(max(yi, 0), H_ - 1);
        const int xc = min(max(xi, 0), W_ - 1);
        ppc[c] = yc * W_ + xc;
        wgt[c] = ok ? wv : 0.f;
        bp[c] = qkb + (size_t)ppc[c] * C_;
    }

    // ---- forced-issue ALL 32 gather loads (payload 128 VGPR) ----
    // byte offsets from bp[c]: q_s = s*64 (0,64,128,192); k_s = 256+s*64.
    u32x4 gq[4][4], gk[4][4];       // [corner][s-phase]
    #pragma unroll
    for (int c = 0; c < 4; ++c) {
        const u16* p = bp[c];
        GLD(gq[c][0], p, "0");   GLD(gq[c][1], p, "64");
        GLD(gq[c][2], p, "128"); GLD(gq[c][3], p, "192");
        GLD(gk[c][0], p, "256"); GLD(gk[c][1], p, "320");
        GLD(gk[c][2], p, "384"); GLD(gk[c][3], p, "448");
    }
    float vsc[4];
    #pragma unroll
    for (int c = 0; c < 4; ++c) vsc[c] = vsm[ppc[c]];
    asm volatile("s_waitcnt vmcnt(0)" ::: "memory");
    __builtin_amdgcn_sched_barrier(0);

    const float vsu_t = wgt[0] * vsc[0] + wgt[1] * vsc[1] +
                        wgt[2] * vsc[2] + wgt[3] * vsc[3];

    // ---- consume ----
    f32x2_t fq[16], fk[16];   // bilinear-accumulated q/k channels (f32x2 pairs)
    #pragma unroll
    for (int e = 0; e < 16; ++e) { fq[e] = (f32x2_t){0.f, 0.f}; fk[e] = (f32x2_t){0.f, 0.f}; }
    #pragma unroll
    for (int s = 0; s < 4; ++s) {
        #pragma unroll
        for (int c = 0; c < 4; ++c) {
            const f32x2_t w2 = {wgt[c], wgt[c]};
            acc8p(&fq[s * 4], gq[c][s], w2);
            acc8p(&fk[s * 4], gk[c][s], w2);
        }
    }

    // 4 MFMA steps: acc[r] = S[i = tap][j = g*4 + r]
    f32x4_t acc = {0.f, 0.f, 0.f, 0.f};
    #pragma unroll
    for (int s = 0; s < 4; ++s) {
        bf16x8_t av, bv;
        #pragma unroll
        for (int e = 0; e < 4; ++e) {
            av[2 * e]     = (__bf16)fk[s * 4 + e].x;   // A = ku (rows j)
            av[2 * e + 1] = (__bf16)fk[s * 4 + e].y;
            bv[2 * e]     = (__bf16)fq[s * 4 + e].x;   // B = qu (cols i)
            bv[2 * e + 1] = (__bf16)fq[s * 4 + e].y;
        }
        acc = __builtin_amdgcn_mfma_f32_16x16x32_bf16(av, bv, acc, 0, 0, 0);
    }

    // softmax over j for fixed i = tap; j spread across lane groups (stride-16 lanes)
    float mx = -1e30f;
    #pragma unroll
    for (int r = 0; r < 4; ++r) {
        const int j = g * 4 + r;
        if (j < K_) mx = fmaxf(mx, acc[r]);
    }
    mx = fmaxf(mx, __shfl_xor(mx, 16, 64));
    mx = fmaxf(mx, __shfl_xor(mx, 32, 64));

    float vj[4];
    #pragma unroll
    for (int r = 0; r < 4; ++r) vj[r] = __shfl(vsu_t, g * 4 + r, 64);  // vsu[j] from lane j

    float den = 0.f, num = 0.f;
    #pragma unroll
    for (int r = 0; r < 4; ++r) {
        const int j = g * 4 + r;
        if (j < K_) {
            const float e = __expf(acc[r] - mx);
            den += e;
            num += e * vj[r];
        }
    }
    den += __shfl_xor(den, 16, 64); den += __shfl_xor(den, 32, 64);
    num += __shfl_xor(num, 16, 64); num += __shfl_xor(num, 32, 64);

    if (l < K_) {
        const float z = num / den + bo[0];
        out[(size_t)b * K_ * NPB_ + (size_t)l * NPB_ + rem] = 1.f / (1.f + __expf(-z));
    }
}

extern "C" void kernel_launch(void* const* d_in, const int* in_sizes, int n_in,
                              void* d_out, int out_size, void* d_ws, size_t ws_size,
                              hipStream_t stream) {
    const float* x   = (const float*)d_in[0];
    const float* off = (const float*)d_in[1];
    const float* Wq  = (const float*)d_in[2];
    const float* bq  = (const float*)d_in[3];
    const float* Wk  = (const float*)d_in[4];
    const float* bk  = (const float*)d_in[5];
    const float* Wv  = (const float*)d_in[6];
    const float* bv  = (const float*)d_in[7];
    const float* Wo  = (const float*)d_in[8];
    const float* bo  = (const float*)d_in[9];
    float* out = (float*)d_out;

    char* ws = (char*)d_ws;
    u16*   qkbuf = (u16*)(ws + 4096);                 // 16384*256 bf16 = 8 MiB
    float* vsmap = (float*)(ws + 4096 + 8388608);     // 16384 f32 = 64 KiB
    u16*   Wt    = (u16*)(ws + 4096 + 8388608 + 65536);        // 272*256 bf16 tiled
    float* bias  = (float*)(ws + 4096 + 8388608 + 65536 + 139264);  // 272 f32

    k0b_prep<<<MROWS_, 256, 0, stream>>>(Wq, bq, Wk, bk, Wv, bv, Wo, Wt, bias);
    k1_proj<<<NP_ / 16, 512, 0, stream>>>(x, Wt, bias, qkbuf, vsmap);
    k2_attn<<<NP_ / 4, 256, 0, stream>>>(off, qkbuf, vsmap, bo, out);
}